// Round 2
// baseline (374.752 us; speedup 1.0000x reference)
//
#include <hip/hip_runtime.h>
#include <math.h>

// Problem constants (from reference)
#define NPTS   65536        // 256*256
#define NB     5            // batch of x
#define NX     25
#define NY     7
#define NZ     6
#define NW     5
#define FG     (NB*NX*NY*NZ*NW)       // 26250 f_grid elements
#define GRID_ELEMS 52500000LL         // 2000 * FG
// out layout: [0]=loss, [1 .. 65536]=theta[0], [65537 ..]=grid_new
// out_grid float index 65537 == 1 (mod 4)  ->  dst 16B-aligned iff e == 3 (mod 4)
#define HEAD   3LL                    // elements 0,1,2 handled in fixup kernel
#define NCH    ((GRID_ELEMS - HEAD) / 4)   // 13,124,999 full chunks
#define TAIL_E (HEAD + 4*NCH)              // 52,499,999 (single tail element)
// ws layout: [0..4]=s[n], [5]=sum|theta|, [6]=sum(f*W4)

typedef float f4  __attribute__((ext_vector_type(4)));               // 16B aligned
typedef float f4u __attribute__((ext_vector_type(4), aligned(4)));   // 4B aligned

// Kernel A: s[n] = sum_i x[n,i]*theta[i] (n=0..4), ws[5] = sum |theta|,
// and copy theta -> out_theta.
__global__ void reduce_kernel(const float* __restrict__ x,
                              const float* __restrict__ theta,
                              float* __restrict__ out_theta,
                              float* __restrict__ ws) {
    __shared__ float smem[4 * 6];   // 4 waves x 6 partials
    int idx = blockIdx.x * blockDim.x + threadIdx.x;   // 0..65535
    float t = theta[idx];
    out_theta[idx] = t;

    float vals[6];
#pragma unroll
    for (int n = 0; n < 5; ++n) vals[n] = x[n * NPTS + idx] * t;
    vals[5] = fabsf(t);

    int lane = threadIdx.x & 63;
    int wave = threadIdx.x >> 6;
#pragma unroll
    for (int k = 0; k < 6; ++k) {
        float v = vals[k];
#pragma unroll
        for (int off = 32; off > 0; off >>= 1) v += __shfl_down(v, off, 64);
        if (lane == 0) smem[wave * 6 + k] = v;
    }
    __syncthreads();
    if (threadIdx.x < 6) {
        float acc = smem[threadIdx.x] + smem[6 + threadIdx.x] +
                    smem[12 + threadIdx.x] + smem[18 + threadIdx.x];
        atomicAdd(&ws[threadIdx.x], acc);
    }
}

// Kernel B1: PURE branch-free streaming copy grid -> out_grid.
// Chunks start at e==3 (mod 4) so stores are 16B-aligned; loads take the
// 4B misalignment. No jptr / ws / atomics in the loop -> compiler can
// pipeline the load->store chain (m13 µbench shape, 6.29 TB/s).
// Slot j is copied stale here and overwritten by Kernel B2 afterwards.
__global__ void __launch_bounds__(256)
copy_kernel(const float* __restrict__ grid,
            float* __restrict__ out_grid) {     // out + 1 + NPTS
    const f4u* __restrict__ src = (const f4u*)(grid + HEAD);
    f4*        __restrict__ dst = (f4*)(out_grid + HEAD);
    const long long stride = (long long)gridDim.x * blockDim.x;
    for (long long c = (long long)blockIdx.x * blockDim.x + threadIdx.x;
         c < NCH; c += stride) {
        dst[c] = (f4)src[c];
    }
}

// f_grid element evaluation (identical arithmetic to the verified kernel)
__device__ __forceinline__ float fgrid_eval(const float* s, int e2, float* w4out) {
    int d  = e2 % NW;
    int cz = (e2 / NW) % NZ;
    int b  = (e2 / (NW * NZ)) % NY;
    int a  = (e2 / (NW * NZ * NY)) % NX;
    int n  = e2 / (NW * NZ * NY * NX);

    const float PI2 = 6.283185307179586f;
    const float dxq = PI2 / 24.0f;
    const float dy = 0.03f;         // 0.18/6
    const float dz = 0.036f;        // 0.18/5
    const float dw = 0.05f;         // 0.2/4

    float xv = PI2 * (float)a / 24.0f;
    float cv = cosf(xv);
    float yv = -0.09f + dy * (float)b;
    float zv = -0.09f + dz * (float)cz;
    float wv = 0.9f + dw * (float)d;

    float arg = s[n] * cv * wv + yv + zv;
    float f = expf(-arg * arg);

    *w4out = dxq * ((a == 0 || a == NX - 1) ? 0.5f : 1.0f)
           * dy  * ((b == 0 || b == NY - 1) ? 0.5f : 1.0f)
           * dz  * ((cz == 0 || cz == NZ - 1) ? 0.5f : 1.0f)
           * dw  * ((d == 0 || d == NW - 1) ? 0.5f : 1.0f);
    return f;
}

// Kernel B2: overwrite slot j with f_grid (26250 contiguous floats),
// accumulate loss partial into ws[6], and patch the 4 edge elements
// (0,1,2,TAIL_E) that the float4 copy skipped.
__global__ void __launch_bounds__(256)
fgrid_kernel(const float* __restrict__ grid,
             float* __restrict__ out_grid,      // out + 1 + NPTS
             const float* __restrict__ ws_in,
             float* __restrict__ ws_out,
             const int* __restrict__ jptr) {
    const int j = *jptr;
    const long long jlo = (long long)j * FG;
    const long long jhi = jlo + FG;

    float s[5];
#pragma unroll
    for (int n = 0; n < 5; ++n) s[n] = ws_in[n];

    float local = 0.0f;
    int e2 = blockIdx.x * blockDim.x + threadIdx.x;
    if (e2 < FG) {
        float w4;
        float f = fgrid_eval(s, e2, &w4);
        out_grid[jlo + e2] = f;
        local = f * w4;
    }

    // edge elements skipped by the vector copy: copy-through when outside
    // slot j (when inside, the loop above already wrote the final value)
    if (blockIdx.x == 0 && threadIdx.x < 4) {
        const long long edge[4] = {0, 1, 2, TAIL_E};
        long long e = edge[threadIdx.x];
        if (e < jlo || e >= jhi) out_grid[e] = grid[e];
    }

    // wave-level reduction of loss contributions, one atomic per wave
#pragma unroll
    for (int off = 32; off > 0; off >>= 1) local += __shfl_down(local, off, 64);
    if ((threadIdx.x & 63) == 0 && local != 0.0f) atomicAdd(&ws_out[6], local);
}

// Kernel C: finalize loss
__global__ void finalize_kernel(const float* __restrict__ ws,
                                float* __restrict__ out) {
    out[0] = ws[6] - 0.5f * ws[5];
}

extern "C" void kernel_launch(void* const* d_in, const int* in_sizes, int n_in,
                              void* d_out, int out_size, void* d_ws, size_t ws_size,
                              hipStream_t stream) {
    const float* x     = (const float*)d_in[0];   // [5,256,256]
    const float* theta = (const float*)d_in[1];   // [1,256,256]
    const float* grid  = (const float*)d_in[2];   // [2000,5,25,7,6,5]
    const int*   jptr  = (const int*)d_in[3];     // scalar

    float* out = (float*)d_out;
    float* ws  = (float*)d_ws;

    // zero reduction scratch (ws is poisoned 0xAA each launch)
    hipMemsetAsync(ws, 0, 7 * sizeof(float), stream);

    // K1: projections + |theta| sum + theta passthrough
    reduce_kernel<<<NPTS / 256, 256, 0, stream>>>(x, theta, out + 1, ws);

    // K2a: pure streaming copy (branch-free, dst-aligned float4)
    copy_kernel<<<16384, 256, 0, stream>>>(grid, out + 1 + NPTS);

    // K2b: slot-j f_grid overwrite + loss partial + edge patch
    fgrid_kernel<<<(FG + 255) / 256, 256, 0, stream>>>(grid, out + 1 + NPTS,
                                                       ws, ws, jptr);

    // K3: finalize loss
    finalize_kernel<<<1, 1, 0, stream>>>(ws, out);
}

// Round 3
// 354.475 us; speedup vs baseline: 1.0572x; 1.0572x over previous
//
#include <hip/hip_runtime.h>
#include <math.h>

// Problem constants (from reference)
#define NPTS   65536        // 256*256
#define NB     5            // batch of x
#define NX     25
#define NY     7
#define NZ     6
#define NW     5
#define FG     (NB*NX*NY*NZ*NW)       // 26250 f_grid elements
#define GRID_ELEMS 52500000LL         // 2000 * FG
// out layout: [0]=loss, [1 .. 65536]=theta[0], [65537 ..]=grid_new
// out_grid float index 65537 == 1 (mod 4)  ->  dst 16B-aligned iff e == 3 (mod 4)
#define HEAD   3LL                    // elements 0,1,2 handled scalar
#define NCH    ((GRID_ELEMS - HEAD) / 4)   // 13,124,999 full chunks
#define TAIL_E (HEAD + 4*NCH)              // 52,499,999 (single tail element)
// ws layout: [0..4]=s[n], [5]=sum|theta|, [6]=sum(f*W4)

typedef float f4  __attribute__((ext_vector_type(4)));               // 16B aligned
typedef float f4u __attribute__((ext_vector_type(4), aligned(4)));   // 4B aligned

// Kernel A: s[n] = sum_i x[n,i]*theta[i] (n=0..4), ws[5] = sum |theta|,
// and copy theta -> out_theta.
__global__ void reduce_kernel(const float* __restrict__ x,
                              const float* __restrict__ theta,
                              float* __restrict__ out_theta,
                              float* __restrict__ ws) {
    __shared__ float smem[4 * 6];   // 4 waves x 6 partials
    int idx = blockIdx.x * blockDim.x + threadIdx.x;   // 0..65535
    float t = theta[idx];
    out_theta[idx] = t;

    float vals[6];
#pragma unroll
    for (int n = 0; n < 5; ++n) vals[n] = x[n * NPTS + idx] * t;
    vals[5] = fabsf(t);

    int lane = threadIdx.x & 63;
    int wave = threadIdx.x >> 6;
#pragma unroll
    for (int k = 0; k < 6; ++k) {
        float v = vals[k];
#pragma unroll
        for (int off = 32; off > 0; off >>= 1) v += __shfl_down(v, off, 64);
        if (lane == 0) smem[wave * 6 + k] = v;
    }
    __syncthreads();
    if (threadIdx.x < 6) {
        float acc = smem[threadIdx.x] + smem[6 + threadIdx.x] +
                    smem[12 + threadIdx.x] + smem[18 + threadIdx.x];
        atomicAdd(&ws[threadIdx.x], acc);
    }
}

// f_grid element evaluation (identical arithmetic to the verified kernel)
__device__ __forceinline__ float fgrid_eval(const float* s, int e2, float* w4out) {
    int d  = e2 % NW;
    int cz = (e2 / NW) % NZ;
    int b  = (e2 / (NW * NZ)) % NY;
    int a  = (e2 / (NW * NZ * NY)) % NX;
    int n  = e2 / (NW * NZ * NY * NX);

    const float PI2 = 6.283185307179586f;
    const float dxq = PI2 / 24.0f;
    const float dy = 0.03f;         // 0.18/6
    const float dz = 0.036f;        // 0.18/5
    const float dw = 0.05f;         // 0.2/4

    float xv = PI2 * (float)a / 24.0f;
    float cv = cosf(xv);
    float yv = -0.09f + dy * (float)b;
    float zv = -0.09f + dz * (float)cz;
    float wv = 0.9f + dw * (float)d;

    float arg = s[n] * cv * wv + yv + zv;
    float f = expf(-arg * arg);

    *w4out = dxq * ((a == 0 || a == NX - 1) ? 0.5f : 1.0f)
           * dy  * ((b == 0 || b == NY - 1) ? 0.5f : 1.0f)
           * dz  * ((cz == 0 || cz == NZ - 1) ? 0.5f : 1.0f)
           * dw  * ((d == 0 || d == NW - 1) ? 0.5f : 1.0f);
    return f;
}

// Kernel B (fused, R1 structure — best measured): float4 grid-stride copy
// grid->out_grid with ALIGNED nontemporal stores (chunks start at e==3
// mod 4; loads take the 4B misalignment). Chunks overlapping slot j
// compute f_grid instead and accumulate loss. nt hints: 420 MB stream has
// zero reuse -> bypass L2 state overhead.
__global__ void __launch_bounds__(256)
copy_fgrid_kernel(const float* __restrict__ grid,
                  float* __restrict__ out_grid,      // out + 1 + NPTS
                  const float* __restrict__ ws_in,
                  float* __restrict__ ws_out,
                  const int* __restrict__ jptr) {
    const int j = *jptr;
    const long long jlo = (long long)j * FG;
    const long long jhi = jlo + FG;

    float s[5];
#pragma unroll
    for (int n = 0; n < 5; ++n) s[n] = ws_in[n];

    float local = 0.0f;
    const long long stride = (long long)gridDim.x * blockDim.x;
    for (long long c = (long long)blockIdx.x * blockDim.x + threadIdx.x;
         c < NCH; c += stride) {
        const long long base = HEAD + c * 4;
        f4 v = (f4)__builtin_nontemporal_load((const f4u*)(grid + base));
        if (base + 3 >= jlo && base < jhi) {
            // rare path: some of the 4 elems lie in slot j -> compute f
#pragma unroll
            for (int q = 0; q < 4; ++q) {
                long long e = base + q;
                if (e >= jlo && e < jhi) {
                    float w4;
                    float f = fgrid_eval(s, (int)(e - jlo), &w4);
                    v[q] = f;
                    local += f * w4;
                }
            }
        }
        __builtin_nontemporal_store(v, (f4*)(out_grid + base));  // 16B-aligned
    }

    // head (e=0,1,2) and tail (e=TAIL_E) handled by a single thread
    if (blockIdx.x == 0 && threadIdx.x == 0) {
        const long long edge[4] = {0, 1, 2, TAIL_E};
#pragma unroll
        for (int t = 0; t < 4; ++t) {
            long long e = edge[t];
            float v = grid[e];
            if (e >= jlo && e < jhi) {
                float w4;
                float f = fgrid_eval(s, (int)(e - jlo), &w4);
                v = f;
                local += f * w4;
            }
            out_grid[e] = v;
        }
    }

    // wave-level reduction of loss contributions, one atomic per wave
#pragma unroll
    for (int off = 32; off > 0; off >>= 1) local += __shfl_down(local, off, 64);
    if ((threadIdx.x & 63) == 0 && local != 0.0f) atomicAdd(&ws_out[6], local);
}

// Kernel C: finalize loss
__global__ void finalize_kernel(const float* __restrict__ ws,
                                float* __restrict__ out) {
    out[0] = ws[6] - 0.5f * ws[5];
}

extern "C" void kernel_launch(void* const* d_in, const int* in_sizes, int n_in,
                              void* d_out, int out_size, void* d_ws, size_t ws_size,
                              hipStream_t stream) {
    const float* x     = (const float*)d_in[0];   // [5,256,256]
    const float* theta = (const float*)d_in[1];   // [1,256,256]
    const float* grid  = (const float*)d_in[2];   // [2000,5,25,7,6,5]
    const int*   jptr  = (const int*)d_in[3];     // scalar

    float* out = (float*)d_out;
    float* ws  = (float*)d_ws;

    // zero reduction scratch (ws is poisoned 0xAA each launch)
    hipMemsetAsync(ws, 0, 7 * sizeof(float), stream);

    // K1: projections + |theta| sum + theta passthrough
    reduce_kernel<<<NPTS / 256, 256, 0, stream>>>(x, theta, out + 1, ws);

    // K2: fused copy + f_grid scatter + loss partial (dst-aligned, nt)
    copy_fgrid_kernel<<<16384, 256, 0, stream>>>(grid, out + 1 + NPTS,
                                                 ws, ws, jptr);

    // K3: finalize loss
    finalize_kernel<<<1, 1, 0, stream>>>(ws, out);
}